// Round 1
// baseline (564.399 us; speedup 1.0000x reference)
//
#include <hip/hip_runtime.h>
#include <cstdint>
#include <cstddef>

typedef __bf16 bf16;
typedef __bf16 bf16x8 __attribute__((ext_vector_type(8)));
typedef __bf16 bf16x4 __attribute__((ext_vector_type(4)));
typedef float f32x4 __attribute__((ext_vector_type(4)));

#define LAMBDA_INIT_F 0.5560582041556405f
#define ONE_MINUS_LI_F 0.4439417958443595f

static constexpr int T = 2048;
static constexpr int ROWQ = 6144;   // qkv row elements: q1|q2|k1|k2|v(2048)
static constexpr float SCALE = 0.125f;  // 1/sqrt(64)

__device__ __forceinline__ f32x4 mfma16(bf16x8 a, bf16x8 b, f32x4 c) {
  return __builtin_amdgcn_mfma_f32_16x16x32_bf16(a, b, c, 0, 0, 0);
}

// ---------------- conversion kernels ----------------

__global__ void cvt_f32_bf16(const float* __restrict__ src, bf16* __restrict__ dst, int n4) {
  int i = blockIdx.x * blockDim.x + threadIdx.x;
  if (i < n4) {
    float4 v = reinterpret_cast<const float4*>(src)[i];
    bf16x4 o;
    o[0] = (bf16)v.x; o[1] = (bf16)v.y; o[2] = (bf16)v.z; o[3] = (bf16)v.w;
    reinterpret_cast<bf16x4*>(dst)[i] = o;
  }
}

// src [K][N] f32  ->  dst [N][K] bf16   (LDS-tiled transpose, block 32x8)
__global__ void transpose_cvt(const float* __restrict__ src, bf16* __restrict__ dst,
                              int K, int N) {
  __shared__ float t[32][33];
  int tx = threadIdx.x, ty = threadIdx.y;
  int n0 = blockIdx.x * 32, k0 = blockIdx.y * 32;
#pragma unroll
  for (int j = 0; j < 32; j += 8)
    t[ty + j][tx] = src[(size_t)(k0 + ty + j) * N + n0 + tx];
  __syncthreads();
#pragma unroll
  for (int j = 0; j < 32; j += 8)
    dst[(size_t)(n0 + ty + j) * K + k0 + tx] = (bf16)t[tx][ty + j];
}

// ---------------- GEMM: A[M,K] bf16  x  Bt[N,K] bf16 -> C[M,N] ----------------

template <typename OutT>
__global__ __launch_bounds__(256) void gemm_bt(const bf16* __restrict__ A,
                                               const bf16* __restrict__ Bt,
                                               OutT* __restrict__ C,
                                               int M, int N, int K) {
  constexpr int LD = 56;  // 32 + pad 24 -> 112B row stride (16B aligned, 2-way banks)
  __shared__ __align__(16) bf16 As[128 * LD];
  __shared__ __align__(16) bf16 Bs[128 * LD];
  const int tid = threadIdx.x;
  const int lane = tid & 63;
  const int w = tid >> 6;
  const int wr = w >> 1, wc = w & 1;
  const int bm = blockIdx.y * 128, bn = blockIdx.x * 128;
  const int lr = lane & 15, lg = lane >> 4;

  f32x4 acc[4][4] = {};

  for (int k0 = 0; k0 < K; k0 += 32) {
    __syncthreads();
#pragma unroll
    for (int i = 0; i < 2; ++i) {
      int c = tid + i * 256;
      int row = c >> 2, off = (c & 3) * 8;
      *reinterpret_cast<bf16x8*>(&As[row * LD + off]) =
          *reinterpret_cast<const bf16x8*>(&A[(size_t)(bm + row) * K + k0 + off]);
      *reinterpret_cast<bf16x8*>(&Bs[row * LD + off]) =
          *reinterpret_cast<const bf16x8*>(&Bt[(size_t)(bn + row) * K + k0 + off]);
    }
    __syncthreads();
    bf16x8 af[4], bfr[4];
#pragma unroll
    for (int m = 0; m < 4; ++m)
      af[m] = *reinterpret_cast<const bf16x8*>(&As[(wr * 64 + m * 16 + lr) * LD + lg * 8]);
#pragma unroll
    for (int n = 0; n < 4; ++n)
      bfr[n] = *reinterpret_cast<const bf16x8*>(&Bs[(wc * 64 + n * 16 + lr) * LD + lg * 8]);
#pragma unroll
    for (int m = 0; m < 4; ++m)
#pragma unroll
      for (int n = 0; n < 4; ++n)
        acc[m][n] = mfma16(af[m], bfr[n], acc[m][n]);
  }

#pragma unroll
  for (int m = 0; m < 4; ++m)
#pragma unroll
    for (int n = 0; n < 4; ++n)
#pragma unroll
      for (int r = 0; r < 4; ++r) {
        int row = bm + wr * 64 + m * 16 + lg * 4 + r;
        int col = bn + wc * 64 + n * 16 + lr;
        C[(size_t)row * N + col] = (OutT)acc[m][n][r];
      }
}

// ---------------- differential flash attention + per-head LayerNorm ----------------
// grid: (T/64, B*16).  block = 256 (4 waves), wave w owns q rows [q0+16w, q0+16w+16)

__global__ __launch_bounds__(256) void diff_attn(const bf16* __restrict__ qkv,
                                                 const float* __restrict__ lq1,
                                                 const float* __restrict__ lk1,
                                                 const float* __restrict__ lq2,
                                                 const float* __restrict__ lk2,
                                                 bf16* __restrict__ yln) {
  constexpr int LDK = 72;  // 144B row stride
  __shared__ __align__(16) bf16 K1s[64 * LDK];
  __shared__ __align__(16) bf16 K2s[64 * LDK];
  __shared__ __align__(16) bf16 Vt[128 * LDK];   // V transposed [d][t], chunk-XOR swizzled
  __shared__ __align__(16) bf16 Ps[4][16 * LDK]; // per-wave P strip

  const int qt = blockIdx.x;
  const int bh = blockIdx.y;
  const int b = bh >> 4, h = bh & 15;
  const int tid = threadIdx.x, lane = tid & 63, w = tid >> 6;
  const int lr = lane & 15, lg = lane >> 4;
  const int q0 = qt * 64;

  const int q1c = h * 64;
  const int q2c = 1024 + h * 64;
  const int k1c = 2048 + h * 64;
  const int k2c = 3072 + h * 64;
  const int vc  = 4096 + h * 128;

  // lambda for this head (wave-parallel dot over 64 elems)
  float a1 = lq1[h * 64 + lane] * lk1[h * 64 + lane];
  float a2 = lq2[h * 64 + lane] * lk2[h * 64 + lane];
#pragma unroll
  for (int m = 32; m >= 1; m >>= 1) {
    a1 += __shfl_xor(a1, m);
    a2 += __shfl_xor(a2, m);
  }
  const float lam = __expf(a1) - __expf(a2) + LAMBDA_INIT_F;

  // Q fragments (held in registers for the whole kernel)
  const int qrow = q0 + w * 16 + lr;
  const bf16* qrowp = qkv + (size_t)(b * T + qrow) * ROWQ;
  bf16x8 q1f[2], q2f[2];
#pragma unroll
  for (int kc = 0; kc < 2; ++kc) {
    q1f[kc] = *reinterpret_cast<const bf16x8*>(qrowp + q1c + kc * 32 + lg * 8);
    q2f[kc] = *reinterpret_cast<const bf16x8*>(qrowp + q2c + kc * 32 + lg * 8);
  }

  f32x4 acc1[8] = {}, acc2[8] = {};
  float m1[4], m2[4], l1[4], l2[4];
#pragma unroll
  for (int r = 0; r < 4; ++r) { m1[r] = -1e30f; m2[r] = -1e30f; l1[r] = 0.f; l2[r] = 0.f; }

  for (int kt = 0; kt <= qt; ++kt) {
    const int t0 = kt * 64;
    __syncthreads();  // previous tile fully consumed
    // ---- stage K1, K2 (row-major [t][hs], pad 72) ----
#pragma unroll
    for (int i = 0; i < 2; ++i) {
      int c = tid + i * 256;
      int tt = c >> 3, hc = (c & 7) * 8;
      const bf16* g = qkv + (size_t)(b * T + t0 + tt) * ROWQ;
      *reinterpret_cast<bf16x8*>(&K1s[tt * LDK + hc]) =
          *reinterpret_cast<const bf16x8*>(g + k1c + hc);
      *reinterpret_cast<bf16x8*>(&K2s[tt * LDK + hc]) =
          *reinterpret_cast<const bf16x8*>(g + k2c + hc);
    }
    // ---- stage V transposed: elem (d,t) at byte d*144 + (((t>>3)^((d>>3)&7))*8 + (t&7))*2
#pragma unroll
    for (int it = 0; it < 4; ++it) {
      int tt = (tid >> 4) + it * 16;
      int dc = tid & 15;
      bf16x8 vv = *reinterpret_cast<const bf16x8*>(
          qkv + (size_t)(b * T + t0 + tt) * ROWQ + vc + dc * 8);
      int sw = (tt >> 3) ^ (dc & 7);
      char* base = reinterpret_cast<char*>(&Vt[0]);
#pragma unroll
      for (int j = 0; j < 8; ++j)
        *reinterpret_cast<bf16*>(base + (dc * 8 + j) * (LDK * 2) + sw * 16 + ((tt & 7) * 2)) = vv[j];
    }
    __syncthreads();

    // ---- S = Q K^T for this wave's 16 rows x 64 cols ----
    f32x4 s1[4] = {}, s2[4] = {};
#pragma unroll
    for (int n = 0; n < 4; ++n) {
#pragma unroll
      for (int kc = 0; kc < 2; ++kc) {
        bf16x8 kf1 = *reinterpret_cast<const bf16x8*>(&K1s[(n * 16 + lr) * LDK + kc * 32 + lg * 8]);
        bf16x8 kf2 = *reinterpret_cast<const bf16x8*>(&K2s[(n * 16 + lr) * LDK + kc * 32 + lg * 8]);
        s1[n] = mfma16(q1f[kc], kf1, s1[n]);
        s2[n] = mfma16(q2f[kc], kf2, s2[n]);
      }
    }

    const bool edge = (kt == qt);
#pragma unroll
    for (int n = 0; n < 4; ++n) {
#pragma unroll
      for (int r = 0; r < 4; ++r) {
        float v1 = s1[n][r] * SCALE;
        float v2 = s2[n][r] * SCALE;
        if (edge) {
          int qq = w * 16 + lg * 4 + r;
          int kk = n * 16 + lr;
          if (kk > qq) { v1 = -1e30f; v2 = -1e30f; }
        }
        s1[n][r] = v1; s2[n][r] = v2;
      }
    }

    // ---- online softmax (two independent states) ----
    float al1[4], al2[4];
#pragma unroll
    for (int r = 0; r < 4; ++r) {
      float rm1 = fmaxf(fmaxf(s1[0][r], s1[1][r]), fmaxf(s1[2][r], s1[3][r]));
      float rm2 = fmaxf(fmaxf(s2[0][r], s2[1][r]), fmaxf(s2[2][r], s2[3][r]));
#pragma unroll
      for (int m = 8; m >= 1; m >>= 1) {
        rm1 = fmaxf(rm1, __shfl_xor(rm1, m));
        rm2 = fmaxf(rm2, __shfl_xor(rm2, m));
      }
      float mn1 = fmaxf(m1[r], rm1);
      float mn2 = fmaxf(m2[r], rm2);
      al1[r] = __expf(m1[r] - mn1);
      al2[r] = __expf(m2[r] - mn2);
      float rs1 = 0.f, rs2 = 0.f;
#pragma unroll
      for (int n = 0; n < 4; ++n) {
        float p1 = __expf(s1[n][r] - mn1);
        float p2 = __expf(s2[n][r] - mn2);
        s1[n][r] = p1; s2[n][r] = p2;
        rs1 += p1; rs2 += p2;
      }
#pragma unroll
      for (int m = 8; m >= 1; m >>= 1) {
        rs1 += __shfl_xor(rs1, m);
        rs2 += __shfl_xor(rs2, m);
      }
      l1[r] = l1[r] * al1[r] + rs1;
      l2[r] = l2[r] * al2[r] + rs2;
      m1[r] = mn1; m2[r] = mn2;
    }
#pragma unroll
    for (int nf = 0; nf < 8; ++nf)
#pragma unroll
      for (int r = 0; r < 4; ++r) { acc1[nf][r] *= al1[r]; acc2[nf][r] *= al2[r]; }

    bf16* Pw = &Ps[w][0];
    // ---- P1 -> LDS -> PV1 ----
#pragma unroll
    for (int n = 0; n < 4; ++n)
#pragma unroll
      for (int r = 0; r < 4; ++r)
        Pw[(lg * 4 + r) * LDK + n * 16 + lr] = (bf16)s1[n][r];
#pragma unroll
    for (int kc = 0; kc < 2; ++kc) {
      bf16x8 pa = *reinterpret_cast<const bf16x8*>(&Pw[lr * LDK + kc * 32 + lg * 8]);
#pragma unroll
      for (int nf = 0; nf < 8; ++nf) {
        int d = nf * 16 + lr;
        int ch = (kc * 4 + lg) ^ ((d >> 3) & 7);
        bf16x8 vb = *reinterpret_cast<const bf16x8*>(
            reinterpret_cast<char*>(&Vt[0]) + d * (LDK * 2) + ch * 16);
        acc1[nf] = mfma16(pa, vb, acc1[nf]);
      }
    }
    // ---- P2 -> LDS -> PV2 (reuse buffer; same-wave ordering is safe) ----
#pragma unroll
    for (int n = 0; n < 4; ++n)
#pragma unroll
      for (int r = 0; r < 4; ++r)
        Pw[(lg * 4 + r) * LDK + n * 16 + lr] = (bf16)s2[n][r];
#pragma unroll
    for (int kc = 0; kc < 2; ++kc) {
      bf16x8 pa = *reinterpret_cast<const bf16x8*>(&Pw[lr * LDK + kc * 32 + lg * 8]);
#pragma unroll
      for (int nf = 0; nf < 8; ++nf) {
        int d = nf * 16 + lr;
        int ch = (kc * 4 + lg) ^ ((d >> 3) & 7);
        bf16x8 vb = *reinterpret_cast<const bf16x8*>(
            reinterpret_cast<char*>(&Vt[0]) + d * (LDK * 2) + ch * 16);
        acc2[nf] = mfma16(pa, vb, acc2[nf]);
      }
    }
  }

  // ---- epilogue: y = att1V - lam*att2V, per-row LayerNorm over 128, write bf16 ----
  float inv1[4], inv2[4];
#pragma unroll
  for (int r = 0; r < 4; ++r) { inv1[r] = 1.f / l1[r]; inv2[r] = lam / l2[r]; }
  float sum[4] = {}, sq[4] = {};
#pragma unroll
  for (int nf = 0; nf < 8; ++nf)
#pragma unroll
    for (int r = 0; r < 4; ++r) {
      float v = acc1[nf][r] * inv1[r] - acc2[nf][r] * inv2[r];
      acc1[nf][r] = v;
      sum[r] += v; sq[r] += v * v;
    }
#pragma unroll
  for (int r = 0; r < 4; ++r) {
#pragma unroll
    for (int m = 8; m >= 1; m >>= 1) {
      sum[r] += __shfl_xor(sum[r], m);
      sq[r] += __shfl_xor(sq[r], m);
    }
  }
#pragma unroll
  for (int r = 0; r < 4; ++r) {
    float mu = sum[r] * (1.f / 128.f);
    float var = sq[r] * (1.f / 128.f) - mu * mu;
    float rs = rsqrtf(var + 1e-5f) * ONE_MINUS_LI_F;
    int row = b * T + q0 + w * 16 + lg * 4 + r;
    bf16* orow = yln + (size_t)row * 2048 + h * 128;
#pragma unroll
    for (int nf = 0; nf < 8; ++nf)
      orow[nf * 16 + lr] = (bf16)((acc1[nf][r] - mu) * rs);
  }
}

// ---------------- launch ----------------

extern "C" void kernel_launch(void* const* d_in, const int* in_sizes, int n_in,
                              void* d_out, int out_size, void* d_ws, size_t ws_size,
                              hipStream_t stream) {
  const float* x   = (const float*)d_in[0];
  const float* q1w = (const float*)d_in[1];
  const float* q2w = (const float*)d_in[2];
  const float* k1w = (const float*)d_in[3];
  const float* k2w = (const float*)d_in[4];
  const float* vw  = (const float*)d_in[5];
  const float* cw  = (const float*)d_in[6];
  const float* lq1 = (const float*)d_in[7];
  const float* lk1 = (const float*)d_in[8];
  const float* lq2 = (const float*)d_in[9];
  const float* lk2 = (const float*)d_in[10];
  float* out = (float*)d_out;

  char* ws = (char*)d_ws;
  bf16* qkv = (bf16*)(ws);                                  // 4096*6144*2 = 50331648
  bf16* Wt  = (bf16*)(ws + 50331648);                       // 6144*1024*2 = 12582912
  bf16* xb  = (bf16*)(ws + 62914560);                       // 4096*1024*2 = 8388608
  bf16* cwt = (bf16*)(ws + 71303168);                       // 1024*2048*2 = 4194304
  bf16* yln = (bf16*)(ws + 75497472);                       // 4096*2048*2 = 16777216

  cvt_f32_bf16<<<4096, 256, 0, stream>>>(x, xb, 4096 * 1024 / 4);

  dim3 tb(32, 8);
  transpose_cvt<<<dim3(32, 32), tb, 0, stream>>>(q1w, Wt,                     1024, 1024);
  transpose_cvt<<<dim3(32, 32), tb, 0, stream>>>(q2w, Wt + 1024 * 1024,       1024, 1024);
  transpose_cvt<<<dim3(32, 32), tb, 0, stream>>>(k1w, Wt + 2048 * 1024,       1024, 1024);
  transpose_cvt<<<dim3(32, 32), tb, 0, stream>>>(k2w, Wt + 3072 * 1024,       1024, 1024);
  transpose_cvt<<<dim3(64, 32), tb, 0, stream>>>(vw,  Wt + 4096 * 1024,       1024, 2048);
  transpose_cvt<<<dim3(32, 64), tb, 0, stream>>>(cw,  cwt,                    2048, 1024);

  // qkv = x @ [q1|q2|k1|k2|v]
  gemm_bt<bf16><<<dim3(48, 32), 256, 0, stream>>>(xb, Wt, qkv, 4096, 6144, 1024);

  // differential attention + per-head LN
  diff_attn<<<dim3(32, 32), 256, 0, stream>>>(qkv, lq1, lk1, lq2, lk2, yln);

  // out = yln @ c_w
  gemm_bt<float><<<dim3(8, 32), 256, 0, stream>>>(yln, cwt, out, 4096, 1024, 2048);
}

// Round 2
// 218.467 us; speedup vs baseline: 2.5835x; 2.5835x over previous
//
#include <hip/hip_runtime.h>
#include <cstdint>
#include <cstddef>

typedef __bf16 bf16;
typedef __bf16 bf16x8 __attribute__((ext_vector_type(8)));
typedef __bf16 bf16x4 __attribute__((ext_vector_type(4)));
typedef float f32x4 __attribute__((ext_vector_type(4)));

#define LAMBDA_INIT_F 0.5560582041556405f
#define ONE_MINUS_LI_F 0.4439417958443595f

static constexpr int T = 2048;
static constexpr int ROWQ = 6144;  // q1|q2|k1|k2|v(2048)

__device__ __forceinline__ f32x4 mfma16(bf16x8 a, bf16x8 b, f32x4 c) {
  return __builtin_amdgcn_mfma_f32_16x16x32_bf16(a, b, c, 0, 0, 0);
}

__device__ __forceinline__ void gld16(const bf16* g, bf16* l) {
  __builtin_amdgcn_global_load_lds(
      (const __attribute__((address_space(1))) void*)g,
      (__attribute__((address_space(3))) void*)l, 16, 0, 0);
}

// ---------------- conversion kernels ----------------

__global__ void cvt_f32_bf16(const float* __restrict__ src, bf16* __restrict__ dst, int n4) {
  int i = blockIdx.x * blockDim.x + threadIdx.x;
  if (i < n4) {
    float4 v = reinterpret_cast<const float4*>(src)[i];
    bf16x4 o;
    o[0] = (bf16)v.x; o[1] = (bf16)v.y; o[2] = (bf16)v.z; o[3] = (bf16)v.w;
    reinterpret_cast<bf16x4*>(dst)[i] = o;
  }
}

// src [K][N] f32 -> dst [N][K] bf16
__global__ void transpose_cvt(const float* __restrict__ src, bf16* __restrict__ dst,
                              int K, int N) {
  __shared__ float t[32][33];
  int tx = threadIdx.x, ty = threadIdx.y;
  int n0 = blockIdx.x * 32, k0 = blockIdx.y * 32;
#pragma unroll
  for (int j = 0; j < 32; j += 8)
    t[ty + j][tx] = src[(size_t)(k0 + ty + j) * N + n0 + tx];
  __syncthreads();
#pragma unroll
  for (int j = 0; j < 32; j += 8)
    dst[(size_t)(n0 + ty + j) * K + k0 + tx] = (bf16)t[tx][ty + j];
}

// V part of qkv -> Vt[bh][d=128][t=2048]
__global__ void vtrans(const bf16* __restrict__ qkv, bf16* __restrict__ Vt) {
  __shared__ bf16 tile[64][72];
  const int tid = threadIdx.x;
  const int t0 = blockIdx.x * 64, dt = blockIdx.y, bh = blockIdx.z;
  const int b = bh >> 4, h = bh & 15;
#pragma unroll
  for (int i = 0; i < 2; ++i) {
    int S = tid + i * 256;
    int r = S >> 3, c = S & 7;
    *reinterpret_cast<bf16x8*>(&tile[r][c * 8]) =
        *reinterpret_cast<const bf16x8*>(
            &qkv[(size_t)(b * T + t0 + r) * ROWQ + 4096 + h * 128 + dt * 64 + c * 8]);
  }
  __syncthreads();
#pragma unroll
  for (int i = 0; i < 2; ++i) {
    int S = tid + i * 256;
    int dr = S >> 3, tc = S & 7;
    bf16x8 v;
#pragma unroll
    for (int j = 0; j < 8; ++j) v[j] = tile[tc * 8 + j][dr];
    *reinterpret_cast<bf16x8*>(
        &Vt[((size_t)bh * 128 + dt * 64 + dr) * 2048 + t0 + tc * 8]) = v;
  }
}

// ---------------- GEMM: A[M,K] x Bt[N,K] -> C[M,N], BK=64, dbuf, gload_lds ----------------

template <typename OutT>
__global__ __launch_bounds__(256, 2) void gemm_bt(const bf16* __restrict__ A,
                                                  const bf16* __restrict__ Bt,
                                                  OutT* __restrict__ C,
                                                  int M, int N, int K) {
  __shared__ __align__(16) bf16 As[2][128 * 64];
  __shared__ __align__(16) bf16 Bs[2][128 * 64];
  const int tid = threadIdx.x;
  const int lane = tid & 63;
  const int wv = tid >> 6;
  const int wr = wv >> 1, wc = wv & 1;
  const int bm = blockIdx.y * 128, bn = blockIdx.x * 128;
  const int lr = lane & 15, lg = lane >> 4;

  f32x4 acc[4][4] = {};
  const int KT = K >> 6;

#define STAGE_AB(buf, kk0)                                                      \
  do {                                                                          \
    _Pragma("unroll") for (int i_ = 0; i_ < 4; ++i_) {                          \
      int S_ = (i_ * 4 + wv) * 64 + lane;                                       \
      int rw_ = S_ >> 3;                                                        \
      int cg_ = (S_ & 7) ^ (rw_ & 7);                                           \
      gld16(&A[(size_t)(bm + rw_) * K + (kk0) + cg_ * 8], &As[buf][(i_ * 4 + wv) * 512]); \
      gld16(&Bt[(size_t)(bn + rw_) * K + (kk0) + cg_ * 8], &Bs[buf][(i_ * 4 + wv) * 512]); \
    }                                                                           \
  } while (0)

  STAGE_AB(0, 0);
  for (int kt = 0; kt < KT; ++kt) {
    const int cur = kt & 1;
    asm volatile("s_waitcnt vmcnt(0)" ::: "memory");
    __syncthreads();
    if (kt + 1 < KT) STAGE_AB(cur ^ 1, (kt + 1) * 64);
#pragma unroll
    for (int kh = 0; kh < 2; ++kh) {
      bf16x8 af[4], bfr[4];
#pragma unroll
      for (int m = 0; m < 4; ++m)
        af[m] = *reinterpret_cast<const bf16x8*>(
            &As[cur][(wr * 64 + m * 16 + lr) * 64 + (((kh * 4 + lg) ^ (lr & 7)) * 8)]);
#pragma unroll
      for (int n = 0; n < 4; ++n)
        bfr[n] = *reinterpret_cast<const bf16x8*>(
            &Bs[cur][(wc * 64 + n * 16 + lr) * 64 + (((kh * 4 + lg) ^ (lr & 7)) * 8)]);
#pragma unroll
      for (int m = 0; m < 4; ++m)
#pragma unroll
        for (int n = 0; n < 4; ++n)
          acc[m][n] = mfma16(af[m], bfr[n], acc[m][n]);
    }
  }
#undef STAGE_AB

#pragma unroll
  for (int m = 0; m < 4; ++m)
#pragma unroll
    for (int n = 0; n < 4; ++n)
#pragma unroll
      for (int r = 0; r < 4; ++r) {
        int row = bm + wr * 64 + m * 16 + lg * 4 + r;
        int col = bn + wc * 64 + n * 16 + lr;
        C[(size_t)row * N + col] = (OutT)acc[m][n][r];
      }
}

// ---------------- differential flash attention + per-head LayerNorm ----------------
// grid (16, 32): block i handles q-tiles {31-i (A), i (B)} for head blockIdx.y.

__global__ __launch_bounds__(256, 2) void diff_attn(const bf16* __restrict__ qkv,
                                                    const bf16* __restrict__ Vtg,
                                                    const float* __restrict__ lq1,
                                                    const float* __restrict__ lk1,
                                                    const float* __restrict__ lq2,
                                                    const float* __restrict__ lk2,
                                                    bf16* __restrict__ yln) {
  constexpr int LDP = 72;
  __shared__ __align__(16) bf16 K1s[2][64 * 64];
  __shared__ __align__(16) bf16 K2s[2][64 * 64];
  __shared__ __align__(16) bf16 Vs[2][128 * 64];
  __shared__ __align__(16) bf16 Ps[4][16 * LDP];

  const int fi = blockIdx.x;
  const int bh = blockIdx.y;
  const int b = bh >> 4, h = bh & 15;
  const int tid = threadIdx.x, lane = tid & 63, wv = tid >> 6;
  const int lr = lane & 15, lg = lane >> 4;
  const int qtA = 31 - fi;  // big tile
  const int qtB = fi;       // small tile

  const int q1c = h * 64;
  const int q2c = 1024 + h * 64;
  const int k1c = 2048 + h * 64;
  const int k2c = 3072 + h * 64;

  // lambda
  float a1 = lq1[h * 64 + lane] * lk1[h * 64 + lane];
  float a2 = lq2[h * 64 + lane] * lk2[h * 64 + lane];
#pragma unroll
  for (int m = 32; m >= 1; m >>= 1) {
    a1 += __shfl_xor(a1, m);
    a2 += __shfl_xor(a2, m);
  }
  const float lam = __expf(a1) - __expf(a2) + LAMBDA_INIT_F;

  bf16x8 onesf;
#pragma unroll
  for (int j = 0; j < 8; ++j) onesf[j] = (bf16)1.0f;

  // Q fragments for both tiles
  bf16x8 q1fA[2], q2fA[2], q1fB[2], q2fB[2];
  {
    const bf16* qa = qkv + (size_t)(b * T + qtA * 64 + wv * 16 + lr) * ROWQ;
    const bf16* qb = qkv + (size_t)(b * T + qtB * 64 + wv * 16 + lr) * ROWQ;
#pragma unroll
    for (int kc = 0; kc < 2; ++kc) {
      q1fA[kc] = *reinterpret_cast<const bf16x8*>(qa + q1c + kc * 32 + lg * 8);
      q2fA[kc] = *reinterpret_cast<const bf16x8*>(qa + q2c + kc * 32 + lg * 8);
      q1fB[kc] = *reinterpret_cast<const bf16x8*>(qb + q1c + kc * 32 + lg * 8);
      q2fB[kc] = *reinterpret_cast<const bf16x8*>(qb + q2c + kc * 32 + lg * 8);
    }
  }

  f32x4 o1A[8] = {}, o2A[8] = {}, o1B[8] = {}, o2B[8] = {};
  f32x4 lA1 = {}, lA2 = {}, lB1 = {}, lB2 = {};

#define STAGE_KV(buf, tt0)                                                       \
  do {                                                                           \
    const bf16* kb_ = qkv + (size_t)(b * T + (tt0)) * ROWQ;                      \
    _Pragma("unroll") for (int i_ = 0; i_ < 2; ++i_) {                           \
      int S_ = (i_ * 4 + wv) * 64 + lane;                                        \
      int rw_ = S_ >> 3;                                                         \
      int cg_ = (S_ & 7) ^ (rw_ & 7);                                            \
      gld16(kb_ + (size_t)rw_ * ROWQ + k1c + cg_ * 8, &K1s[buf][(i_ * 4 + wv) * 512]); \
      gld16(kb_ + (size_t)rw_ * ROWQ + k2c + cg_ * 8, &K2s[buf][(i_ * 4 + wv) * 512]); \
    }                                                                            \
    _Pragma("unroll") for (int i_ = 0; i_ < 4; ++i_) {                           \
      int S_ = (i_ * 4 + wv) * 64 + lane;                                        \
      int dd_ = S_ >> 3;                                                         \
      int cg_ = (S_ & 7) ^ (dd_ & 7);                                            \
      gld16(Vtg + ((size_t)bh * 128 + dd_) * 2048 + (tt0) + cg_ * 8,             \
            &Vs[buf][(i_ * 4 + wv) * 512]);                                      \
    }                                                                            \
  } while (0)

#define ATT_STEP(q1f_, q2f_, o1_, o2_, l1_, l2_, edge_)                          \
  do {                                                                           \
    f32x4 s1_[4] = {}, s2_[4] = {};                                              \
    _Pragma("unroll") for (int n_ = 0; n_ < 4; ++n_) {                           \
      int krow_ = n_ * 16 + lr;                                                  \
      _Pragma("unroll") for (int kc_ = 0; kc_ < 2; ++kc_) {                      \
        bf16x8 kf1_ = *reinterpret_cast<const bf16x8*>(                          \
            &K1s[cur][krow_ * 64 + (((kc_ * 4 + lg) ^ (lr & 7)) * 8)]);          \
        bf16x8 kf2_ = *reinterpret_cast<const bf16x8*>(                          \
            &K2s[cur][krow_ * 64 + (((kc_ * 4 + lg) ^ (lr & 7)) * 8)]);          \
        s1_[n_] = mfma16(q1f_[kc_], kf1_, s1_[n_]);                              \
        s2_[n_] = mfma16(q2f_[kc_], kf2_, s2_[n_]);                              \
      }                                                                          \
    }                                                                            \
    _Pragma("unroll") for (int n_ = 0; n_ < 4; ++n_)                             \
    _Pragma("unroll") for (int r_ = 0; r_ < 4; ++r_) {                           \
      float e1_ = fmaf(s1_[n_][r_], 0.125f, -16.0f);                             \
      float e2_ = fmaf(s2_[n_][r_], 0.125f, -16.0f);                             \
      if (edge_) {                                                               \
        int qq_ = wv * 16 + lg * 4 + r_;                                         \
        int kk_ = n_ * 16 + lr;                                                  \
        if (kk_ > qq_) { e1_ = -1e4f; e2_ = -1e4f; }                             \
      }                                                                          \
      s1_[n_][r_] = __expf(e1_);                                                 \
      s2_[n_][r_] = __expf(e2_);                                                 \
    }                                                                            \
    bf16* Pw_ = &Ps[wv][0];                                                      \
    bf16x8 pa1_[2], pa2_[2];                                                     \
    _Pragma("unroll") for (int n_ = 0; n_ < 4; ++n_)                             \
    _Pragma("unroll") for (int r_ = 0; r_ < 4; ++r_)                             \
        Pw_[(lg * 4 + r_) * LDP + n_ * 16 + lr] = (bf16)s1_[n_][r_];             \
    _Pragma("unroll") for (int kc_ = 0; kc_ < 2; ++kc_)                          \
        pa1_[kc_] = *reinterpret_cast<const bf16x8*>(&Pw_[lr * LDP + kc_ * 32 + lg * 8]); \
    _Pragma("unroll") for (int n_ = 0; n_ < 4; ++n_)                             \
    _Pragma("unroll") for (int r_ = 0; r_ < 4; ++r_)                             \
        Pw_[(lg * 4 + r_) * LDP + n_ * 16 + lr] = (bf16)s2_[n_][r_];             \
    _Pragma("unroll") for (int kc_ = 0; kc_ < 2; ++kc_)                          \
        pa2_[kc_] = *reinterpret_cast<const bf16x8*>(&Pw_[lr * LDP + kc_ * 32 + lg * 8]); \
    _Pragma("unroll") for (int kc_ = 0; kc_ < 2; ++kc_) {                        \
      l1_ = mfma16(pa1_[kc_], onesf, l1_);                                       \
      l2_ = mfma16(pa2_[kc_], onesf, l2_);                                       \
      _Pragma("unroll") for (int nf_ = 0; nf_ < 8; ++nf_) {                      \
        int dd_ = nf_ * 16 + lr;                                                 \
        bf16x8 vb_ = *reinterpret_cast<const bf16x8*>(                           \
            &Vs[cur][dd_ * 64 + (((kc_ * 4 + lg) ^ (lr & 7)) * 8)]);             \
        o1_[nf_] = mfma16(pa1_[kc_], vb_, o1_[nf_]);                             \
        o2_[nf_] = mfma16(pa2_[kc_], vb_, o2_[nf_]);                             \
      }                                                                          \
    }                                                                            \
  } while (0)

  STAGE_KV(0, 0);
  for (int kt = 0; kt <= qtA; ++kt) {
    const int cur = kt & 1;
    asm volatile("s_waitcnt vmcnt(0)" ::: "memory");
    __syncthreads();
    if (kt < qtA) STAGE_KV(cur ^ 1, (kt + 1) * 64);
    ATT_STEP(q1fA, q2fA, o1A, o2A, lA1, lA2, (kt == qtA));
    if (kt <= qtB) ATT_STEP(q1fB, q2fB, o1B, o2B, lB1, lB2, (kt == qtB));
  }
#undef ATT_STEP
#undef STAGE_KV

#define ATT_EPI(o1_, o2_, l1_, l2_, qt_)                                         \
  do {                                                                           \
    float sum_[4] = {}, sq_[4] = {};                                             \
    float i1_[4], i2_[4];                                                        \
    _Pragma("unroll") for (int r_ = 0; r_ < 4; ++r_) {                           \
      i1_[r_] = 1.f / l1_[r_];                                                   \
      i2_[r_] = lam / l2_[r_];                                                   \
    }                                                                            \
    _Pragma("unroll") for (int nf_ = 0; nf_ < 8; ++nf_)                          \
    _Pragma("unroll") for (int r_ = 0; r_ < 4; ++r_) {                           \
      float v_ = o1_[nf_][r_] * i1_[r_] - o2_[nf_][r_] * i2_[r_];                \
      o1_[nf_][r_] = v_;                                                         \
      sum_[r_] += v_;                                                            \
      sq_[r_] += v_ * v_;                                                        \
    }                                                                            \
    _Pragma("unroll") for (int r_ = 0; r_ < 4; ++r_)                             \
    _Pragma("unroll") for (int mm_ = 8; mm_ >= 1; mm_ >>= 1) {                   \
      sum_[r_] += __shfl_xor(sum_[r_], mm_);                                     \
      sq_[r_] += __shfl_xor(sq_[r_], mm_);                                       \
    }                                                                            \
    _Pragma("unroll") for (int r_ = 0; r_ < 4; ++r_) {                           \
      float mu_ = sum_[r_] * (1.f / 128.f);                                      \
      float var_ = sq_[r_] * (1.f / 128.f) - mu_ * mu_;                          \
      float rs_ = rsqrtf(var_ + 1e-5f) * ONE_MINUS_LI_F;                         \
      int row_ = b * T + (qt_)*64 + wv * 16 + lg * 4 + r_;                       \
      bf16* orow_ = yln + (size_t)row_ * 2048 + h * 128;                         \
      _Pragma("unroll") for (int nf_ = 0; nf_ < 8; ++nf_)                        \
          orow_[nf_ * 16 + lr] = (bf16)((o1_[nf_][r_] - mu_) * rs_);             \
    }                                                                            \
  } while (0)

  ATT_EPI(o1A, o2A, lA1, lA2, qtA);
  ATT_EPI(o1B, o2B, lB1, lB2, qtB);
#undef ATT_EPI
}

// ---------------- launch ----------------

extern "C" void kernel_launch(void* const* d_in, const int* in_sizes, int n_in,
                              void* d_out, int out_size, void* d_ws, size_t ws_size,
                              hipStream_t stream) {
  const float* x   = (const float*)d_in[0];
  const float* q1w = (const float*)d_in[1];
  const float* q2w = (const float*)d_in[2];
  const float* k1w = (const float*)d_in[3];
  const float* k2w = (const float*)d_in[4];
  const float* vw  = (const float*)d_in[5];
  const float* cw  = (const float*)d_in[6];
  const float* lq1 = (const float*)d_in[7];
  const float* lk1 = (const float*)d_in[8];
  const float* lq2 = (const float*)d_in[9];
  const float* lk2 = (const float*)d_in[10];
  float* out = (float*)d_out;

  char* ws = (char*)d_ws;
  bf16* qkv = (bf16*)(ws);                 // 50331648 B
  bf16* Wt  = (bf16*)(ws + 50331648);      // 12582912 B (dead after gemm1)
  bf16* xb  = (bf16*)(ws + 62914560);      // 8388608 B  (dead after gemm1)
  bf16* cwt = (bf16*)(ws + 71303168);      // 4194304 B
  bf16* yln = (bf16*)(ws + 75497472);      // 16777216 B
  bf16* Vt  = (bf16*)(ws + 50331648);      // 16777216 B, reuses Wt+xb region

  cvt_f32_bf16<<<4096, 256, 0, stream>>>(x, xb, 4096 * 1024 / 4);

  dim3 tb(32, 8);
  transpose_cvt<<<dim3(32, 32), tb, 0, stream>>>(q1w, Wt,               1024, 1024);
  transpose_cvt<<<dim3(32, 32), tb, 0, stream>>>(q2w, Wt + 1024 * 1024, 1024, 1024);
  transpose_cvt<<<dim3(32, 32), tb, 0, stream>>>(k1w, Wt + 2048 * 1024, 1024, 1024);
  transpose_cvt<<<dim3(32, 32), tb, 0, stream>>>(k2w, Wt + 3072 * 1024, 1024, 1024);
  transpose_cvt<<<dim3(64, 32), tb, 0, stream>>>(vw,  Wt + 4096 * 1024, 1024, 2048);
  transpose_cvt<<<dim3(32, 64), tb, 0, stream>>>(cw,  cwt,              2048, 1024);

  // qkv = x @ [q1|q2|k1|k2|v]
  gemm_bt<bf16><<<dim3(48, 32), 256, 0, stream>>>(xb, Wt, qkv, 4096, 6144, 1024);

  // Vt[bh][d][t]
  vtrans<<<dim3(32, 2, 32), 256, 0, stream>>>(qkv, Vt);

  // differential attention + per-head LN (folded causal grid)
  diff_attn<<<dim3(16, 32), 256, 0, stream>>>(qkv, Vt, lq1, lk1, lq2, lk2, yln);

  // out = yln @ c_w
  gemm_bt<float><<<dim3(8, 32), 256, 0, stream>>>(yln, cwt, out, 4096, 1024, 2048);
}